// Round 2
// baseline (1312.074 us; speedup 1.0000x reference)
//
#include <hip/hip_runtime.h>

typedef _Float16 half8 __attribute__((ext_vector_type(8)));
typedef _Float16 half4 __attribute__((ext_vector_type(4)));
typedef float    f32x4 __attribute__((ext_vector_type(4)));

#define MFMA32(a,b,c) __builtin_amdgcn_mfma_f32_16x16x32_f16(a,b,c,0,0,0)
#define MFMA16(a,b,c) __builtin_amdgcn_mfma_f32_16x16x16f16(a,b,c,0,0,0)

#if __has_builtin(__builtin_amdgcn_exp2f)
#define EXP2F(x) __builtin_amdgcn_exp2f(x)
#else
#define EXP2F(x) exp2f(x)
#endif

// scale = DH^-0.5 = 1/8, folded together with log2(e) into Q so softmax uses exp2.
static constexpr float SCALE_LOG2E = 0.18033688011112042f;

// ---------------------------------------------------------------------------
// K1: qkv projection. C[8192,1536] = X[8192,512] @ W[512,1536] + b.
// Scatters to Qh[b][h][n][64] (xSCALE_LOG2E), Kh[b][h][n][64], Vt[b][h][64][n], all f16.
// ---------------------------------------------------------------------------
__global__ __launch_bounds__(256)
void k_qkv(const float* __restrict__ x, const float* __restrict__ w,
           const float* __restrict__ bias, _Float16* __restrict__ Qh,
           _Float16* __restrict__ Kh, _Float16* __restrict__ Vt)
{
  __shared__ __align__(16) _Float16 Xs[64*40];
  __shared__ __align__(16) _Float16 Wt[64*40];
  const int tid = threadIdx.x;
  const int wv = tid >> 6, lane = tid & 63, l15 = lane & 15, qd = lane >> 4;
  const int row0 = blockIdx.y * 64, col0 = blockIdx.x * 64;

  const int xr = tid >> 2, xc = (tid & 3) * 8;
  const int wk = tid >> 3, wc = (tid & 7) * 8;

  f32x4 acc[4] = {{0.f,0.f,0.f,0.f},{0.f,0.f,0.f,0.f},{0.f,0.f,0.f,0.f},{0.f,0.f,0.f,0.f}};

  for (int k0 = 0; k0 < 512; k0 += 32) {
    f32x4 a0 = *(const f32x4*)(x + (size_t)(row0 + xr) * 512 + k0 + xc);
    f32x4 a1 = *(const f32x4*)(x + (size_t)(row0 + xr) * 512 + k0 + xc + 4);
    f32x4 b0 = *(const f32x4*)(w + (size_t)(k0 + wk) * 1536 + col0 + wc);
    f32x4 b1 = *(const f32x4*)(w + (size_t)(k0 + wk) * 1536 + col0 + wc + 4);
    half8 hx;
#pragma unroll
    for (int j = 0; j < 4; j++) { hx[j] = (_Float16)a0[j]; hx[j+4] = (_Float16)a1[j]; }
    *(half8*)&Xs[xr*40 + xc] = hx;
#pragma unroll
    for (int j = 0; j < 4; j++) {
      Wt[(wc+j  )*40 + wk] = (_Float16)b0[j];
      Wt[(wc+j+4)*40 + wk] = (_Float16)b1[j];
    }
    __syncthreads();
    half8 af = *(const half8*)&Xs[(wv*16 + l15)*40 + qd*8];
#pragma unroll
    for (int ct = 0; ct < 4; ct++) {
      half8 bf = *(const half8*)&Wt[(ct*16 + l15)*40 + qd*8];
      acc[ct] = MFMA32(af, bf, acc[ct]);
    }
    __syncthreads();
  }
#pragma unroll
  for (int ct = 0; ct < 4; ct++) {
    const int c = col0 + ct*16 + l15;
    const int sec = c >> 9, hh = (c >> 6) & 7, d = c & 63;
    const float bv = bias[c];
#pragma unroll
    for (int i = 0; i < 4; i++) {
      const int row = row0 + wv*16 + qd*4 + i;
      const int bb = row >> 11, n = row & 2047;
      float v = acc[ct][i] + bv;
      if (sec == 0)
        Qh[((size_t)((bb*8 + hh)*2048 + n))*64 + d] = (_Float16)(v * SCALE_LOG2E);
      else if (sec == 1)
        Kh[((size_t)((bb*8 + hh)*2048 + n))*64 + d] = (_Float16)v;
      else
        Vt[((size_t)((bb*8 + hh)*64 + d))*2048 + n] = (_Float16)v;
    }
  }
}

// ---------------------------------------------------------------------------
// K2: pass 1 — partial softmax denominators over an m-quarter.
// atomicAdd into Lsum[b,g,n] (zeroed before launch). Grid 1024 = 4b x 64nt x 4mq.
// ---------------------------------------------------------------------------
__global__ __launch_bounds__(256, 4)
void k_pass1(const _Float16* __restrict__ Qh, const _Float16* __restrict__ Kh,
             const float* __restrict__ th1, float* __restrict__ Lsum)
{
  __shared__ __align__(16) _Float16 Ks[8*32*72];  // 8h x 32m x 64d(+8 pad)
  const int tid = threadIdx.x;
  const int wv = tid >> 6, lane = tid & 63, l15 = lane & 15, qd = lane >> 4;
  const int b = blockIdx.x >> 8, nt = (blockIdx.x >> 2) & 63, mq = blockIdx.x & 3;
  const int n0 = nt*32 + (wv >> 1)*16;
  const int p = wv & 1;

  float t1[4][8];
#pragma unroll
  for (int gg = 0; gg < 4; gg++)
#pragma unroll
    for (int h = 0; h < 8; h++)
      t1[gg][h] = th1[(p*4 + gg)*8 + h];

  half8 qf[8][2];
#pragma unroll
  for (int h = 0; h < 8; h++)
#pragma unroll
    for (int kc = 0; kc < 2; kc++)
      qf[h][kc] = *(const half8*)(Qh + ((size_t)((b*8 + h)*2048 + n0 + l15))*64 + kc*32 + qd*8);

  f32x4 lsum[4] = {{0.f,0.f,0.f,0.f},{0.f,0.f,0.f,0.f},{0.f,0.f,0.f,0.f},{0.f,0.f,0.f,0.f}};

  const int sh = tid >> 5, sm = tid & 31;
  const _Float16* ksrc0 = Kh + ((size_t)((b*8 + sh)*2048 + sm))*64;
  _Float16* kdst = &Ks[(sh*32 + sm)*72];

  for (int it = 0; it < 16; it++) {
    const int m0 = mq*512 + it*32;
    const _Float16* s = ksrc0 + (size_t)m0*64;
#pragma unroll
    for (int j = 0; j < 8; j++)
      *(half8*)(kdst + j*8) = *(const half8*)(s + j*8);
    __syncthreads();
#pragma unroll
    for (int mc = 0; mc < 2; mc++) {
      f32x4 sp[4] = {{0.f,0.f,0.f,0.f},{0.f,0.f,0.f,0.f},{0.f,0.f,0.f,0.f},{0.f,0.f,0.f,0.f}};
#pragma unroll
      for (int h = 0; h < 8; h++) {
        const _Float16* kb = &Ks[(h*32 + mc*16 + l15)*72 + qd*8];
        half8 kb0 = *(const half8*)kb;
        half8 kb1 = *(const half8*)(kb + 32);
        f32x4 s4 = {0.f,0.f,0.f,0.f};
        s4 = MFMA32(qf[h][0], kb0, s4);
        s4 = MFMA32(qf[h][1], kb1, s4);
#pragma unroll
        for (int gg = 0; gg < 4; gg++)
          sp[gg] += t1[gg][h] * s4;
      }
#pragma unroll
      for (int gg = 0; gg < 4; gg++)
#pragma unroll
        for (int i = 0; i < 4; i++)
          lsum[gg][i] += EXP2F(sp[gg][i]);
    }
    __syncthreads();
  }

#pragma unroll
  for (int gg = 0; gg < 4; gg++)
#pragma unroll
    for (int i = 0; i < 4; i++) {
      float v = lsum[gg][i];
      v += __shfl_xor(v, 1);
      v += __shfl_xor(v, 2);
      v += __shfl_xor(v, 4);
      v += __shfl_xor(v, 8);
      if (l15 == 0)
        atomicAdd(&Lsum[(size_t)(b*8 + p*4 + gg)*2048 + n0 + qd*4 + i], v);
    }
}

// ---------------------------------------------------------------------------
// K3: pass 2 over an m-half. Waves = (n-subtile x m-chunk): each wave computes
// scores (K direct from global), th1 mix, exp2*invl, th2 mix ONCE for its 16m
// chunk (all 8 heads), writes W to LDS; PV waves split by g-range over both
// chunks. Partial O written per m-half; k_oproj sums. Grid 512 = 4b x 64nt x 2mh.
// ---------------------------------------------------------------------------
__global__ __launch_bounds__(256, 2)
void k_pass2(const _Float16* __restrict__ Qh, const _Float16* __restrict__ Kh,
             const _Float16* __restrict__ Vt, const float* __restrict__ Lsum,
             const float* __restrict__ th1, const float* __restrict__ th2,
             _Float16* __restrict__ Obuf)
{
  __shared__ __align__(16) _Float16 Vs[8*64*36];    // 36864 B : [g*64+d][32m +4]
  __shared__ __align__(16) _Float16 Wl[2*8*16*36];  // 18432 B : [(ns*8+g)*16+n][32m +4]
  const int tid = threadIdx.x;
  const int wv = tid >> 6, lane = tid & 63, l15 = lane & 15, qd = lane >> 4;
  const int b = blockIdx.x >> 7, nt = (blockIdx.x >> 1) & 63, mh = blockIdx.x & 1;
  const int ns = wv >> 1, mp = wv & 1, p = mp;
  const int n0 = nt*32 + ns*16;

  float t1[8][8], t2[8][8];
#pragma unroll
  for (int g = 0; g < 8; g++)
#pragma unroll
    for (int h = 0; h < 8; h++) {
      t1[g][h] = th1[g*8 + h];
      t2[g][h] = th2[g*8 + h];
    }
  f32x4 invl[8];
#pragma unroll
  for (int h = 0; h < 8; h++)
#pragma unroll
    for (int i = 0; i < 4; i++)
      invl[h][i] = 1.0f / Lsum[(size_t)(b*8 + h)*2048 + n0 + qd*4 + i];

  half8 qf[8][2];
#pragma unroll
  for (int h = 0; h < 8; h++)
#pragma unroll
    for (int kc = 0; kc < 2; kc++)
      qf[h][kc] = *(const half8*)(Qh + ((size_t)((b*8 + h)*2048 + n0 + l15))*64 + kc*32 + qd*8);

  f32x4 og[4][4];
#pragma unroll
  for (int gg = 0; gg < 4; gg++)
#pragma unroll
    for (int dt = 0; dt < 4; dt++)
      og[gg][dt] = (f32x4){0.f,0.f,0.f,0.f};

  const _Float16* vbase = Vt + (size_t)b*512*2048;
  const int vrow = tid >> 1, vmh = (tid & 1)*16;

  for (int it = 0; it < 32; it++) {
    const int mm = mh*1024 + it*32;
    // stage V tile: 512 (g,d) rows x 32 m
#pragma unroll
    for (int rr = 0; rr < 4; rr++) {
      const int row = rr*128 + vrow;
      const _Float16* s = vbase + (size_t)row*2048 + mm + vmh;
      half8 v0 = *(const half8*)s;
      half8 v1 = *(const half8*)(s + 8);
      _Float16* d = &Vs[row*36 + vmh];
      *(half8*)d = v0;
      *(half8*)(d + 8) = v1;
    }
    __syncthreads();

    // scores for this wave's 16m chunk (K direct from global), th1-mixed
    f32x4 sp[8];
#pragma unroll
    for (int g = 0; g < 8; g++) sp[g] = (f32x4){0.f,0.f,0.f,0.f};
#pragma unroll
    for (int h = 0; h < 8; h++) {
      const _Float16* kb = Kh + ((size_t)((b*8 + h)*2048 + mm + mp*16 + l15))*64 + qd*8;
      half8 kb0 = *(const half8*)kb;
      half8 kb1 = *(const half8*)(kb + 32);
      f32x4 s4 = {0.f,0.f,0.f,0.f};
      s4 = MFMA32(qf[h][0], kb0, s4);
      s4 = MFMA32(qf[h][1], kb1, s4);
#pragma unroll
      for (int g = 0; g < 8; g++)
        sp[g] += t1[g][h] * s4;
    }
    // softmax weights (precomputed 1/l), th2 mix across heads
    f32x4 wacc[8];
#pragma unroll
    for (int g = 0; g < 8; g++) wacc[g] = (f32x4){0.f,0.f,0.f,0.f};
#pragma unroll
    for (int h = 0; h < 8; h++) {
      f32x4 pr;
#pragma unroll
      for (int i = 0; i < 4; i++)
        pr[i] = EXP2F(sp[h][i]);
      pr *= invl[h];
#pragma unroll
      for (int g = 0; g < 8; g++)
        wacc[g] += t2[g][h] * pr;
    }
    // write W (C-layout -> LDS rows) for this (ns, m-chunk)
#pragma unroll
    for (int g = 0; g < 8; g++)
#pragma unroll
      for (int i = 0; i < 4; i++)
        Wl[((ns*8 + g)*16 + qd*4 + i)*36 + mp*16 + l15] = (_Float16)wacc[g][i];
    __syncthreads();

    // PV: this wave handles g in [p*4, p*4+4) over BOTH m-chunks
#pragma unroll
    for (int gg = 0; gg < 4; gg++) {
      const int g = p*4 + gg;
#pragma unroll
      for (int mc = 0; mc < 2; mc++) {
        half4 af = *(const half4*)&Wl[((ns*8 + g)*16 + l15)*36 + mc*16 + qd*4];
#pragma unroll
        for (int dt = 0; dt < 4; dt++) {
          half4 bf = *(const half4*)&Vs[(g*64 + dt*16 + l15)*36 + mc*16 + qd*4];
          og[gg][dt] = MFMA16(af, bf, og[gg][dt]);
        }
      }
    }
    __syncthreads();
  }

  _Float16* Op = Obuf + (size_t)mh * 8192 * 512;   // partial buffer for this m-half
#pragma unroll
  for (int gg = 0; gg < 4; gg++)
#pragma unroll
    for (int dt = 0; dt < 4; dt++)
#pragma unroll
      for (int i = 0; i < 4; i++) {
        const int col = (p*4 + gg)*64 + dt*16 + l15;
        const int n = n0 + qd*4 + i;
        Op[((size_t)(b*2048 + n))*512 + col] = (_Float16)og[gg][dt][i];
      }
}

// ---------------------------------------------------------------------------
// K4: output projection with partial-O sum.
// out[8192,512] = (O0+O1)[8192,512] @ w_out[512,512] + b_out (fp32 out)
// ---------------------------------------------------------------------------
__global__ __launch_bounds__(256)
void k_oproj(const _Float16* __restrict__ A0, const _Float16* __restrict__ A1,
             const float* __restrict__ w, const float* __restrict__ bias,
             float* __restrict__ out)
{
  __shared__ __align__(16) _Float16 Xs[64*40];
  __shared__ __align__(16) _Float16 Wt[64*40];
  const int tid = threadIdx.x;
  const int wv = tid >> 6, lane = tid & 63, l15 = lane & 15, qd = lane >> 4;
  const int row0 = blockIdx.y * 64, col0 = blockIdx.x * 64;
  const int xr = tid >> 2, xc = (tid & 3) * 8;
  const int wk = tid >> 3, wc = (tid & 7) * 8;

  f32x4 acc[4] = {{0.f,0.f,0.f,0.f},{0.f,0.f,0.f,0.f},{0.f,0.f,0.f,0.f},{0.f,0.f,0.f,0.f}};

  for (int k0 = 0; k0 < 512; k0 += 32) {
    half8 a0 = *(const half8*)(A0 + (size_t)(row0 + xr)*512 + k0 + xc);
    half8 a1 = *(const half8*)(A1 + (size_t)(row0 + xr)*512 + k0 + xc);
    *(half8*)&Xs[xr*40 + xc] = a0 + a1;
    f32x4 b0 = *(const f32x4*)(w + (size_t)(k0 + wk)*512 + col0 + wc);
    f32x4 b1 = *(const f32x4*)(w + (size_t)(k0 + wk)*512 + col0 + wc + 4);
#pragma unroll
    for (int j = 0; j < 4; j++) {
      Wt[(wc+j  )*40 + wk] = (_Float16)b0[j];
      Wt[(wc+j+4)*40 + wk] = (_Float16)b1[j];
    }
    __syncthreads();
    half8 af = *(const half8*)&Xs[(wv*16 + l15)*40 + qd*8];
#pragma unroll
    for (int ct = 0; ct < 4; ct++) {
      half8 bf = *(const half8*)&Wt[(ct*16 + l15)*40 + qd*8];
      acc[ct] = MFMA32(af, bf, acc[ct]);
    }
    __syncthreads();
  }
#pragma unroll
  for (int ct = 0; ct < 4; ct++) {
    const int c = col0 + ct*16 + l15;
    const float bv = bias[c];
#pragma unroll
    for (int i = 0; i < 4; i++) {
      const int row = row0 + wv*16 + qd*4 + i;
      out[(size_t)row*512 + c] = acc[ct][i] + bv;
    }
  }
}

// ---------------------------------------------------------------------------
extern "C" void kernel_launch(void* const* d_in, const int* in_sizes, int n_in,
                              void* d_out, int out_size, void* d_ws, size_t ws_size,
                              hipStream_t stream)
{
  (void)in_sizes; (void)n_in; (void)out_size;
  const float* x     = (const float*)d_in[0];
  const float* w_qkv = (const float*)d_in[1];
  const float* b_qkv = (const float*)d_in[2];
  const float* th1   = (const float*)d_in[3];
  const float* th2   = (const float*)d_in[4];
  const float* w_out = (const float*)d_in[5];
  const float* b_out = (const float*)d_in[6];
  float* out = (float*)d_out;

  char* ws = (char*)d_ws;
  _Float16* Qh   = (_Float16*)(ws);
  _Float16* Kh   = (_Float16*)(ws + ((size_t)8  << 20));
  _Float16* Vt   = (_Float16*)(ws + ((size_t)16 << 20));
  float*    Lsum = (float*)   (ws + ((size_t)24 << 20));
  _Float16* O0   = (_Float16*)(ws + ((size_t)25 << 20));
  _Float16* O1   = (_Float16*)(ws + ((size_t)33 << 20));
  if (ws_size < ((size_t)41 << 20)) return;  // need 41 MB scratch

  hipMemsetAsync(Lsum, 0, (size_t)4*8*2048*sizeof(float), stream);
  k_qkv  <<<dim3(24, 128), 256, 0, stream>>>(x, w_qkv, b_qkv, Qh, Kh, Vt);
  k_pass1<<<dim3(1024),    256, 0, stream>>>(Qh, Kh, th1, Lsum);
  k_pass2<<<dim3(512),     256, 0, stream>>>(Qh, Kh, Vt, Lsum, th1, th2, O0);
  k_oproj<<<dim3(8, 128),  256, 0, stream>>>(O0, O1, w_out, b_out, out);
}

// Round 3
// 568.024 us; speedup vs baseline: 2.3099x; 2.3099x over previous
//
#include <hip/hip_runtime.h>

typedef _Float16 half8 __attribute__((ext_vector_type(8)));
typedef _Float16 half4 __attribute__((ext_vector_type(4)));
typedef float    f32x4 __attribute__((ext_vector_type(4)));

#define MFMA32(a,b,c) __builtin_amdgcn_mfma_f32_16x16x32_f16(a,b,c,0,0,0)

#if __has_builtin(__builtin_amdgcn_exp2f)
#define EXP2F(x) __builtin_amdgcn_exp2f(x)
#else
#define EXP2F(x) exp2f(x)
#endif

// scale = DH^-0.5 = 1/8, folded together with log2(e) into Q so softmax uses exp2.
static constexpr float SCALE_LOG2E = 0.18033688011112042f;

static constexpr size_t QH_OFF = 0;
static constexpr size_t KH_OFF = (size_t)8  << 20;
static constexpr size_t VT_OFF = (size_t)16 << 20;
static constexpr size_t LS_OFF = (size_t)24 << 20;
static constexpr size_t O_OFF  = (size_t)25 << 20;
static constexpr size_t LPART  = (size_t)4*8*2048;       // floats per L partial
static constexpr size_t OPART  = (size_t)8192*512;       // halves per O partial

// ---------------------------------------------------------------------------
// K1: qkv projection. C[8192,1536] = X[8192,512] @ W[512,1536] + b.
// Scatters to Qh[b][h][n][64] (xSCALE_LOG2E), Kh[b][h][n][64], Vt[b][h][64][n], all f16.
// Grid (128 row-tiles, 24 col-tiles): same-XCD blocks share an X row-stripe.
// ---------------------------------------------------------------------------
__global__ __launch_bounds__(256)
void k_qkv(const float* __restrict__ x, const float* __restrict__ w,
           const float* __restrict__ bias, _Float16* __restrict__ Qh,
           _Float16* __restrict__ Kh, _Float16* __restrict__ Vt)
{
  __shared__ __align__(16) _Float16 Xs[64*40];
  __shared__ __align__(16) _Float16 Wt[64*40];
  const int tid = threadIdx.x;
  const int wv = tid >> 6, lane = tid & 63, l15 = lane & 15, qd = lane >> 4;
  const int row0 = blockIdx.x * 64, col0 = blockIdx.y * 64;

  const int xr = tid >> 2, xc = (tid & 3) * 8;
  const int wk = tid >> 3, wc = (tid & 7) * 8;

  f32x4 acc[4] = {{0.f,0.f,0.f,0.f},{0.f,0.f,0.f,0.f},{0.f,0.f,0.f,0.f},{0.f,0.f,0.f,0.f}};

  for (int k0 = 0; k0 < 512; k0 += 32) {
    f32x4 a0 = *(const f32x4*)(x + (size_t)(row0 + xr) * 512 + k0 + xc);
    f32x4 a1 = *(const f32x4*)(x + (size_t)(row0 + xr) * 512 + k0 + xc + 4);
    f32x4 b0 = *(const f32x4*)(w + (size_t)(k0 + wk) * 1536 + col0 + wc);
    f32x4 b1 = *(const f32x4*)(w + (size_t)(k0 + wk) * 1536 + col0 + wc + 4);
    half8 hx;
#pragma unroll
    for (int j = 0; j < 4; j++) { hx[j] = (_Float16)a0[j]; hx[j+4] = (_Float16)a1[j]; }
    *(half8*)&Xs[xr*40 + xc] = hx;
#pragma unroll
    for (int j = 0; j < 4; j++) {
      Wt[(wc+j  )*40 + wk] = (_Float16)b0[j];
      Wt[(wc+j+4)*40 + wk] = (_Float16)b1[j];
    }
    __syncthreads();
    half8 af = *(const half8*)&Xs[(wv*16 + l15)*40 + qd*8];
#pragma unroll
    for (int ct = 0; ct < 4; ct++) {
      half8 bf = *(const half8*)&Wt[(ct*16 + l15)*40 + qd*8];
      acc[ct] = MFMA32(af, bf, acc[ct]);
    }
    __syncthreads();
  }
#pragma unroll
  for (int ct = 0; ct < 4; ct++) {
    const int c = col0 + ct*16 + l15;
    const int sec = c >> 9, hh = (c >> 6) & 7, d = c & 63;
    const float bv = bias[c];
#pragma unroll
    for (int i = 0; i < 4; i++) {
      const int row = row0 + wv*16 + qd*4 + i;
      const int bb = row >> 11, n = row & 2047;
      float v = acc[ct][i] + bv;
      if (sec == 0)
        Qh[((size_t)((bb*8 + hh)*2048 + n))*64 + d] = (_Float16)(v * SCALE_LOG2E);
      else if (sec == 1)
        Kh[((size_t)((bb*8 + hh)*2048 + n))*64 + d] = (_Float16)v;
      else
        Vt[((size_t)((bb*8 + hh)*64 + d))*2048 + n] = (_Float16)v;
    }
  }
}

// ---------------------------------------------------------------------------
// K2: pass 1 — partial softmax denominators over an m-quarter. Plain stores to
// per-mq partial buffers (NO atomics). Grid 1024: blockIdx = nt*16 + (b*4+mq)
// so same-XCD blocks (idx%8) share one (b,mq) K-slice (~1 MB in L2).
// Waves (ns,mp): each computes its own 16m chunk, all 8 h + all 8 g (no dup).
// ---------------------------------------------------------------------------
__global__ __launch_bounds__(256, 3)
void k_pass1(const _Float16* __restrict__ Qh, const _Float16* __restrict__ Kh,
             const float* __restrict__ th1, float* __restrict__ Lsum)
{
  __shared__ __align__(16) _Float16 Ks[8*32*72];  // 36864 B
  __shared__ float Lred[2][8][16];                // 1 KB
  const int tid = threadIdx.x;
  const int wv = tid >> 6, lane = tid & 63, l15 = lane & 15, qd = lane >> 4;
  const int s = blockIdx.x & 15, nt = blockIdx.x >> 4;
  const int b = s >> 2, mq = s & 3;
  const int ns = wv >> 1, mp = wv & 1;
  const int n0 = nt*32 + ns*16;

  float t1[8][8];
#pragma unroll
  for (int g = 0; g < 8; g++)
#pragma unroll
    for (int h = 0; h < 8; h++)
      t1[g][h] = th1[g*8 + h];

  half8 qf[8][2];
#pragma unroll
  for (int h = 0; h < 8; h++)
#pragma unroll
    for (int kc = 0; kc < 2; kc++)
      qf[h][kc] = *(const half8*)(Qh + ((size_t)((b*8 + h)*2048 + n0 + l15))*64 + kc*32 + qd*8);

  f32x4 lsum[8];
#pragma unroll
  for (int g = 0; g < 8; g++) lsum[g] = (f32x4){0.f,0.f,0.f,0.f};

  const int sh = tid >> 5, sm = tid & 31;
  const _Float16* ksrc0 = Kh + ((size_t)((b*8 + sh)*2048 + sm))*64;
  _Float16* kdst = &Ks[(sh*32 + sm)*72];

  for (int it = 0; it < 16; it++) {
    const int m0 = mq*512 + it*32;
    const _Float16* sv = ksrc0 + (size_t)m0*64;
#pragma unroll
    for (int j = 0; j < 8; j++)
      *(half8*)(kdst + j*8) = *(const half8*)(sv + j*8);
    __syncthreads();

    f32x4 sp[8];
#pragma unroll
    for (int g = 0; g < 8; g++) sp[g] = (f32x4){0.f,0.f,0.f,0.f};
#pragma unroll
    for (int h = 0; h < 8; h++) {
      const _Float16* kb = &Ks[(h*32 + mp*16 + l15)*72 + qd*8];
      half8 kb0 = *(const half8*)kb;
      half8 kb1 = *(const half8*)(kb + 32);
      f32x4 s4 = {0.f,0.f,0.f,0.f};
      s4 = MFMA32(qf[h][0], kb0, s4);
      s4 = MFMA32(qf[h][1], kb1, s4);
#pragma unroll
      for (int g = 0; g < 8; g++)
        sp[g] += t1[g][h] * s4;
    }
#pragma unroll
    for (int g = 0; g < 8; g++)
#pragma unroll
      for (int i = 0; i < 4; i++)
        lsum[g][i] += EXP2F(sp[g][i]);
    __syncthreads();
  }

  // reduce over the 16 m-columns held across l15 lanes
#pragma unroll
  for (int g = 0; g < 8; g++)
#pragma unroll
    for (int i = 0; i < 4; i++) {
      float v = lsum[g][i];
      v += __shfl_xor(v, 1);
      v += __shfl_xor(v, 2);
      v += __shfl_xor(v, 4);
      v += __shfl_xor(v, 8);
      lsum[g][i] = v;
    }
  if (mp == 1 && l15 == 0) {
#pragma unroll
    for (int g = 0; g < 8; g++)
#pragma unroll
      for (int i = 0; i < 4; i++)
        Lred[ns][g][qd*4 + i] = lsum[g][i];
  }
  __syncthreads();
  if (mp == 0 && l15 == 0) {
    float* Lp = Lsum + (size_t)mq * LPART;
#pragma unroll
    for (int g = 0; g < 8; g++)
#pragma unroll
      for (int i = 0; i < 4; i++)
        Lp[(size_t)(b*8 + g)*2048 + n0 + qd*4 + i] = lsum[g][i] + Lred[ns][g][qd*4 + i];
  }
}

// ---------------------------------------------------------------------------
// K3: pass 2 over an m-quarter. Normalization folded into the exp2 seed
// (sp init = -log2 l). Each wave: scores for its own 16m chunk (K direct from
// global, XCD-local), th1 mix, exp2, th2 mix, W->LDS; PV via 16x16x32 MFMA
// split by g-range over the full 32m. Partial O per mq; k_oproj sums 4.
// Grid 1024: blockIdx = nt*16 + (b*4+mq) (XCD swizzle).
// ---------------------------------------------------------------------------
__global__ __launch_bounds__(256, 2)
void k_pass2(const _Float16* __restrict__ Qh, const _Float16* __restrict__ Kh,
             const _Float16* __restrict__ Vt, const float* __restrict__ Lsum,
             const float* __restrict__ th1, const float* __restrict__ th2,
             _Float16* __restrict__ Obuf)
{
  __shared__ __align__(16) _Float16 Vs[512*34];   // 34816 B : [g*64+d][32m +2]
  __shared__ __align__(16) _Float16 Wl[256*34];   // 17408 B : [(ns*8+g)*16+n][32m +2]
  const int tid = threadIdx.x;
  const int wv = tid >> 6, lane = tid & 63, l15 = lane & 15, qd = lane >> 4;
  const int s = blockIdx.x & 15, nt = blockIdx.x >> 4;
  const int b = s >> 2, mq = s & 3;
  const int ns = wv >> 1, mp = wv & 1, p = mp;
  const int n0 = nt*32 + ns*16;

  float t1[8][8], t2[8][8];
#pragma unroll
  for (int g = 0; g < 8; g++)
#pragma unroll
    for (int h = 0; h < 8; h++) {
      t1[g][h] = th1[g*8 + h];
      t2[g][h] = th2[g*8 + h];
    }
  // seed = -log2(sum of 4 L partials)
  f32x4 nlg[8];
#pragma unroll
  for (int h = 0; h < 8; h++)
#pragma unroll
    for (int i = 0; i < 4; i++) {
      const size_t off = (size_t)(b*8 + h)*2048 + n0 + qd*4 + i;
      float l = Lsum[off] + Lsum[off + LPART] + Lsum[off + 2*LPART] + Lsum[off + 3*LPART];
      nlg[h][i] = -__log2f(l);
    }

  half8 qf[8][2];
#pragma unroll
  for (int h = 0; h < 8; h++)
#pragma unroll
    for (int kc = 0; kc < 2; kc++)
      qf[h][kc] = *(const half8*)(Qh + ((size_t)((b*8 + h)*2048 + n0 + l15))*64 + kc*32 + qd*8);

  f32x4 og[4][4];
#pragma unroll
  for (int gg = 0; gg < 4; gg++)
#pragma unroll
    for (int dt = 0; dt < 4; dt++)
      og[gg][dt] = (f32x4){0.f,0.f,0.f,0.f};

  const _Float16* vbase = Vt + (size_t)b*512*2048;

  for (int it = 0; it < 16; it++) {
    const int mm = mq*512 + it*32;

    // scores for this wave's 16m chunk (K direct from global), th1-mixed, seeded
    f32x4 sp[8];
#pragma unroll
    for (int g = 0; g < 8; g++) sp[g] = nlg[g];
#pragma unroll
    for (int h = 0; h < 8; h++) {
      const _Float16* kb = Kh + ((size_t)((b*8 + h)*2048 + mm + mp*16 + l15))*64 + qd*8;
      half8 kb0 = *(const half8*)kb;
      half8 kb1 = *(const half8*)(kb + 32);
      f32x4 s4 = {0.f,0.f,0.f,0.f};
      s4 = MFMA32(qf[h][0], kb0, s4);
      s4 = MFMA32(qf[h][1], kb1, s4);
#pragma unroll
      for (int g = 0; g < 8; g++)
        sp[g] += t1[g][h] * s4;
    }
    // p = exp2(sp) is already normalized; th2 mix across heads
    f32x4 wacc[8];
#pragma unroll
    for (int g = 0; g < 8; g++) wacc[g] = (f32x4){0.f,0.f,0.f,0.f};
#pragma unroll
    for (int g = 0; g < 8; g++) {
      f32x4 pr;
#pragma unroll
      for (int i = 0; i < 4; i++)
        pr[i] = EXP2F(sp[g][i]);
#pragma unroll
      for (int g2 = 0; g2 < 8; g2++)
        wacc[g2] += t2[g2][g] * pr;
    }
    // write W (C-layout -> LDS rows) for this (ns, m-chunk)
#pragma unroll
    for (int g = 0; g < 8; g++)
#pragma unroll
      for (int i = 0; i < 4; i++)
        Wl[((ns*8 + g)*16 + qd*4 + i)*34 + mp*16 + l15] = (_Float16)wacc[g][i];

    // stage V tile: 512 (g,d) rows x 32 m (before the same barrier)
#pragma unroll
    for (int rr = 0; rr < 2; rr++) {
      const int row = rr*256 + tid;
      const _Float16* sv = vbase + (size_t)row*2048 + mm;
      _Float16* d = &Vs[row*34];
#pragma unroll
      for (int j = 0; j < 4; j++)
        *(half8*)(d + j*8) = *(const half8*)(sv + j*8);
    }
    __syncthreads();

    // PV: this wave handles g in [p*4, p*4+4) over the full 32m (16x16x32)
#pragma unroll
    for (int gg = 0; gg < 4; gg++) {
      const int g = p*4 + gg;
      half8 af = *(const half8*)&Wl[((ns*8 + g)*16 + l15)*34 + qd*8];
#pragma unroll
      for (int dt = 0; dt < 4; dt++) {
        half8 bf = *(const half8*)&Vs[(g*64 + dt*16 + l15)*34 + qd*8];
        og[gg][dt] = MFMA32(af, bf, og[gg][dt]);
      }
    }
    __syncthreads();
  }

  _Float16* Op = Obuf + (size_t)mq * OPART;   // partial buffer for this m-quarter
#pragma unroll
  for (int gg = 0; gg < 4; gg++)
#pragma unroll
    for (int dt = 0; dt < 4; dt++)
#pragma unroll
      for (int i = 0; i < 4; i++) {
        const int col = (p*4 + gg)*64 + dt*16 + l15;
        const int n = n0 + qd*4 + i;
        Op[((size_t)(b*2048 + n))*512 + col] = (_Float16)og[gg][dt][i];
      }
}

// ---------------------------------------------------------------------------
// K4: output projection summing 4 partial O buffers.
// out[8192,512] = (O0+O1+O2+O3) @ w_out[512,512] + b_out (fp32 out)
// Grid (128 row-tiles, 8 col-tiles).
// ---------------------------------------------------------------------------
__global__ __launch_bounds__(256)
void k_oproj(const _Float16* __restrict__ Ob, const float* __restrict__ w,
             const float* __restrict__ bias, float* __restrict__ out)
{
  __shared__ __align__(16) _Float16 Xs[64*40];
  __shared__ __align__(16) _Float16 Wt[64*40];
  const int tid = threadIdx.x;
  const int wv = tid >> 6, lane = tid & 63, l15 = lane & 15, qd = lane >> 4;
  const int row0 = blockIdx.x * 64, col0 = blockIdx.y * 64;
  const int xr = tid >> 2, xc = (tid & 3) * 8;
  const int wk = tid >> 3, wc = (tid & 7) * 8;

  f32x4 acc[4] = {{0.f,0.f,0.f,0.f},{0.f,0.f,0.f,0.f},{0.f,0.f,0.f,0.f},{0.f,0.f,0.f,0.f}};

  for (int k0 = 0; k0 < 512; k0 += 32) {
    const size_t idx = (size_t)(row0 + xr)*512 + k0 + xc;
    half8 a0 = *(const half8*)(Ob + idx);
    half8 a1 = *(const half8*)(Ob + OPART + idx);
    half8 a2 = *(const half8*)(Ob + 2*OPART + idx);
    half8 a3 = *(const half8*)(Ob + 3*OPART + idx);
    *(half8*)&Xs[xr*40 + xc] = (a0 + a1) + (a2 + a3);
    f32x4 b0 = *(const f32x4*)(w + (size_t)(k0 + wk)*512 + col0 + wc);
    f32x4 b1 = *(const f32x4*)(w + (size_t)(k0 + wk)*512 + col0 + wc + 4);
#pragma unroll
    for (int j = 0; j < 4; j++) {
      Wt[(wc+j  )*40 + wk] = (_Float16)b0[j];
      Wt[(wc+j+4)*40 + wk] = (_Float16)b1[j];
    }
    __syncthreads();
    half8 af = *(const half8*)&Xs[(wv*16 + l15)*40 + qd*8];
#pragma unroll
    for (int ct = 0; ct < 4; ct++) {
      half8 bf = *(const half8*)&Wt[(ct*16 + l15)*40 + qd*8];
      acc[ct] = MFMA32(af, bf, acc[ct]);
    }
    __syncthreads();
  }
#pragma unroll
  for (int ct = 0; ct < 4; ct++) {
    const int c = col0 + ct*16 + l15;
    const float bv = bias[c];
#pragma unroll
    for (int i = 0; i < 4; i++) {
      const int row = row0 + wv*16 + qd*4 + i;
      out[(size_t)row*512 + c] = acc[ct][i] + bv;
    }
  }
}

// ---------------------------------------------------------------------------
extern "C" void kernel_launch(void* const* d_in, const int* in_sizes, int n_in,
                              void* d_out, int out_size, void* d_ws, size_t ws_size,
                              hipStream_t stream)
{
  (void)in_sizes; (void)n_in; (void)out_size;
  const float* x     = (const float*)d_in[0];
  const float* w_qkv = (const float*)d_in[1];
  const float* b_qkv = (const float*)d_in[2];
  const float* th1   = (const float*)d_in[3];
  const float* th2   = (const float*)d_in[4];
  const float* w_out = (const float*)d_in[5];
  const float* b_out = (const float*)d_in[6];
  float* out = (float*)d_out;

  char* ws = (char*)d_ws;
  _Float16* Qh   = (_Float16*)(ws + QH_OFF);
  _Float16* Kh   = (_Float16*)(ws + KH_OFF);
  _Float16* Vt   = (_Float16*)(ws + VT_OFF);
  float*    Lsum = (float*)   (ws + LS_OFF);
  _Float16* Obuf = (_Float16*)(ws + O_OFF);
  if (ws_size < ((size_t)58 << 20)) return;  // need 58 MB scratch

  k_qkv  <<<dim3(128, 24), 256, 0, stream>>>(x, w_qkv, b_qkv, Qh, Kh, Vt);
  k_pass1<<<dim3(1024),    256, 0, stream>>>(Qh, Kh, th1, Lsum);
  k_pass2<<<dim3(1024),    256, 0, stream>>>(Qh, Kh, Vt, Lsum, th1, th2, Obuf);
  k_oproj<<<dim3(128, 8),  256, 0, stream>>>(Obuf, w_out, b_out, out);
}